// Round 16
// baseline (364.523 us; speedup 1.0000x reference)
//
#include <hip/hip_runtime.h>

#define KK2 25
#define FIN 64
#define HH 16
#define CC 7
#define KSPLIT 5

#define SCAN_VPT 4
#define SCAN_BLK 256
#define SCAN_CHUNK (SCAN_VPT * SCAN_BLK)   // 1024 elements per block

__device__ inline unsigned short f2bf(float f) {   // RNE float->bf16
    unsigned u = __float_as_uint(f);
    return (unsigned short)((u + 0x7FFFu + ((u >> 16) & 1u)) >> 16);
}
__device__ inline float bf2f(unsigned short b) {   // exact bf16->float
    return __uint_as_float(((unsigned)b) << 16);
}

// ---------------- histogram of dst degrees (int atomics) ----------------
__global__ void k_hist(const int* __restrict__ ei, int* __restrict__ cnt, int E) {
    int e = blockIdx.x * 256 + threadIdx.x;
    if (e < E) atomicAdd(&cnt[ei[E + e]], 1);
}

// ---------------- scan pass 1: per-block sums ----------------
__global__ void k_bsum(const int* __restrict__ cnt, int* __restrict__ bsum, int N) {
    int b = blockIdx.x, t = threadIdx.x;
    int base = b * SCAN_CHUNK + t * SCAN_VPT;
    int s = 0;
#pragma unroll
    for (int j = 0; j < SCAN_VPT; j++) {
        int i = base + j;
        if (i < N) s += cnt[i];
    }
#pragma unroll
    for (int d = 1; d < 64; d <<= 1) s += __shfl_xor(s, d, 64);
    __shared__ int sd[SCAN_BLK / 64];
    if ((t & 63) == 0) sd[t >> 6] = s;
    __syncthreads();
    if (t == 0) {
        int tot = 0;
        for (int w = 0; w < SCAN_BLK / 64; w++) tot += sd[w];
        bsum[b] = tot;
    }
}

// ---------------- scan pass 2: scan the block sums (single small block) ----------------
__global__ void k_bscan(const int* __restrict__ bsum, int* __restrict__ boff, int nblk) {
    int t = threadIdx.x;            // 256 threads, nblk <= 256
    __shared__ int sd[256];
    int v = (t < nblk) ? bsum[t] : 0;
    sd[t] = v;
    __syncthreads();
    for (int off = 1; off < 256; off <<= 1) {
        int u = (t >= off) ? sd[t - off] : 0;
        __syncthreads();
        sd[t] += u;
        __syncthreads();
    }
    boff[t] = sd[t] - v;            // exclusive prefix
}

// ---------------- scan pass 3: local scan + block offset -> rowStart, cursor ----------------
__global__ void k_sfin(const int* __restrict__ cnt, const int* __restrict__ boff,
                       int* __restrict__ rowStart, int* __restrict__ cursor, int N) {
    int b = blockIdx.x, t = threadIdx.x;
    int base = b * SCAN_CHUNK + t * SCAN_VPT;
    int v[SCAN_VPT];
    int s = 0;
#pragma unroll
    for (int j = 0; j < SCAN_VPT; j++) {
        int i = base + j;
        v[j] = (i < N) ? cnt[i] : 0;
        s += v[j];
    }
    __shared__ int sd[SCAN_BLK];
    sd[t] = s;
    __syncthreads();
    for (int off = 1; off < SCAN_BLK; off <<= 1) {
        int u = (t >= off) ? sd[t - off] : 0;
        __syncthreads();
        sd[t] += u;
        __syncthreads();
    }
    int run = sd[t] - s + boff[b];
#pragma unroll
    for (int j = 0; j < SCAN_VPT; j++) {
        int i = base + j;
        if (i < N) {
            rowStart[i] = run;
            cursor[i] = run;
            run += v[j];
            if (i == N - 1) rowStart[N] = run;
        }
    }
}

// ---------------- scatter edges into dst-sorted order, packed 16B records ----------------
// rec[pos] = {bf16 b.x|b.y, bf16 b.z|b.w, src, wiPack}
__global__ void k_scatter(const float* __restrict__ attr, const int* __restrict__ ei,
                          int* __restrict__ cursor, uint4* __restrict__ rec, int E) {
    int e = blockIdx.x * 256 + threadIdx.x;
    if (e >= E) return;
    float v0 = attr[2 * e] * 4.0f, v1 = attr[2 * e + 1] * 4.0f;
    float l0 = floorf(v0), l1 = floorf(v1);
    float f0 = v0 - l0, f1 = v1 - l1;
    int i0 = (int)l0, i1 = (int)l1;
    int i0a = min(max(i0, 0), 4), i0b = min(max(i0 + 1, 0), 4);
    int i1a = min(max(i1, 0), 4), i1b = min(max(i1 + 1, 0), 4);
    float bx = (1.0f - f0) * (1.0f - f1);
    float by = f0 * (1.0f - f1);
    float bz = (1.0f - f0) * f1;
    float bw = f0 * f1;
    unsigned pack = (unsigned)(i0a * 5 + i1a) | ((unsigned)(i0b * 5 + i1a) << 8) |
                    ((unsigned)(i0a * 5 + i1b) << 16) | ((unsigned)(i0b * 5 + i1b) << 24);
    int s = ei[e], d = ei[E + e];
    int pos = atomicAdd(&cursor[d], 1);
    uint4 r;
    r.x = (unsigned)f2bf(bx) | ((unsigned)f2bf(by) << 16);
    r.y = (unsigned)f2bf(bz) | ((unsigned)f2bf(bw) << 16);
    r.z = (unsigned)s;
    r.w = pack;
    rec[pos] = r;
}

// ---------------- repack weights: B1t for k_y1, W2t[k][c][i] for k_agg2d ----------------
__global__ void k_prepW(const float* __restrict__ W1, const float* __restrict__ W2,
                        float* __restrict__ B1t, float* __restrict__ W2t) {
    int tid = blockIdx.x * 256 + threadIdx.x;
    if (tid < KK2 * FIN * HH) {
        int c = tid >> 6, i = tid & 63;
        int k = c >> 4, h = c & 15;
        B1t[tid] = W1[(k * FIN + i) * HH + h];
    }
    if (tid < KK2 * 8 * HH) {        // W2t[(k*8+c)*16+i] = W2[k][i][c], pad c=7
        int k = tid >> 7, r = tid & 127;
        int c = r >> 4, i = r & 15;
        W2t[tid] = (c < CC) ? W2[(k * HH + i) * CC + c] : 0.0f;
    }
}

// ---------------- y1T[k][n][16] bf16 = (x @ W1[k])[n]  (r8-verified: 64.7us) ----------------
// KSPLIT ks per block (x row read once per 5 k). Output staged via LDS so each
// global store instruction is lane-contiguous 1KB (full 64B lines -> amp 1.0).
__global__ void k_y1(const float* __restrict__ x, const float* __restrict__ B1t,
                     unsigned short* __restrict__ y1Tb, int N, int nbl) {
    __shared__ uint4 sh[4][144];             // 128 + pad
    int kg = blockIdx.x / nbl;               // 0..KSPLIT-1, block-uniform
    int nwin = blockIdx.x % nbl;
    int n = nwin * 256 + threadIdx.x;
    int wv = threadIdx.x >> 6, lane = threadIdx.x & 63;
    bool active = (n < N);
    float4 xr[16];
    if (active) {
        const float4* xp = (const float4*)(x + (size_t)n * 64);
#pragma unroll
        for (int i = 0; i < 16; i++) xr[i] = xp[i];
    }
    int nwb = nwin * 256 + wv * 64;          // wave's base node
    int valid = min(64, max(0, N - nwb)) * 2;  // valid uint4s in wave's 2KB

    for (int dk = 0; dk < KSPLIT; dk++) {
        int k = kg * KSPLIT + dk;
        const float* B = B1t + k * 16 * 64;  // 4KB, L1-resident, block-uniform
        unsigned tmp[8];
        if (active) {
#pragma unroll
            for (int h4 = 0; h4 < 4; h4++) {
                float a0 = 0, a1 = 0, a2 = 0, a3 = 0;
                const float4* b0 = (const float4*)(B + (h4 * 4 + 0) * 64);
                const float4* b1 = (const float4*)(B + (h4 * 4 + 1) * 64);
                const float4* b2 = (const float4*)(B + (h4 * 4 + 2) * 64);
                const float4* b3 = (const float4*)(B + (h4 * 4 + 3) * 64);
#pragma unroll
                for (int i = 0; i < 16; i++) {
                    float4 xi = xr[i];
                    float4 v0 = b0[i], v1 = b1[i], v2 = b2[i], v3 = b3[i];
                    a0 += xi.x * v0.x + xi.y * v0.y + xi.z * v0.z + xi.w * v0.w;
                    a1 += xi.x * v1.x + xi.y * v1.y + xi.z * v1.z + xi.w * v1.w;
                    a2 += xi.x * v2.x + xi.y * v2.y + xi.z * v2.z + xi.w * v2.w;
                    a3 += xi.x * v3.x + xi.y * v3.y + xi.z * v3.z + xi.w * v3.w;
                }
                tmp[h4 * 2 + 0] = (unsigned)f2bf(a0) | ((unsigned)f2bf(a1) << 16);
                tmp[h4 * 2 + 1] = (unsigned)f2bf(a2) | ((unsigned)f2bf(a3) << 16);
            }
        } else {
#pragma unroll
            for (int j = 0; j < 8; j++) tmp[j] = 0;
        }
        // stage: thread t owns uint4 indices 2t, 2t+1 (padded: idx + idx/8)
        int i0 = lane * 2, i1 = lane * 2 + 1;
        sh[wv][i0 + (i0 >> 3)] = make_uint4(tmp[0], tmp[1], tmp[2], tmp[3]);
        sh[wv][i1 + (i1 >> 3)] = make_uint4(tmp[4], tmp[5], tmp[6], tmp[7]);
        __syncthreads();
        // drain: lane-contiguous -> two 1KB fully-covered store instructions
        uint4* gbase = (uint4*)(y1Tb + ((size_t)k * N + nwb) * 16);
        int j0 = lane, j1 = lane + 64;
        if (j0 < valid) gbase[j0] = sh[wv][j0 + (j0 >> 3)];
        if (j1 < valid) gbase[j1] = sh[wv][j1 + (j1 >> 3)];
        __syncthreads();
    }
}

// ---------------- fused layer-1: gather + mean + root1 + bias1 + relu -> h1 ----------------
__global__ void k_agg1u(const int* __restrict__ rowStart, const uint4* __restrict__ rec,
                        const unsigned short* __restrict__ y1Tb, const float* __restrict__ x,
                        const float* __restrict__ root1, const float* __restrict__ bias1,
                        float* __restrict__ h1, int N) {
    int n = blockIdx.x * 4 + (threadIdx.x >> 6);
    if (n >= N) return;
    int lane = threadIdx.x & 63;
    int sub = lane >> 4, h = lane & 15;
    int start = rowStart[n], end = rowStart[n + 1];
    float acc = 0.0f;
    size_t NN = (size_t)N;
    for (int i = start + sub; i < end; i += 4) {
        uint4 r = rec[i];
        float bx = bf2f((unsigned short)(r.x & 0xffffu));
        float by = bf2f((unsigned short)(r.x >> 16));
        float bz = bf2f((unsigned short)(r.y & 0xffffu));
        float bw = bf2f((unsigned short)(r.y >> 16));
        int s = (int)r.z;
        unsigned w = r.w;
        acc += bx * bf2f(y1Tb[((w & 255u) * NN + s) * 16 + h]);
        acc += by * bf2f(y1Tb[(((w >> 8) & 255u) * NN + s) * 16 + h]);
        acc += bz * bf2f(y1Tb[(((w >> 16) & 255u) * NN + s) * 16 + h]);
        acc += bw * bf2f(y1Tb[((w >> 24) * NN + s) * 16 + h]);
    }
    acc += __shfl_xor(acc, 16, 64);
    acc += __shfl_xor(acc, 32, 64);
    // all lanes now hold the total for their h; apply node update redundantly
    float inv = 1.0f / (float)max(end - start, 1);
    float rv = acc * inv + bias1[h];
    const float* xrow = x + (size_t)n * 64;
#pragma unroll 8
    for (int i = 0; i < 64; i++) rv += xrow[i] * root1[i * 16 + h];
    rv = fmaxf(rv, 0.0f);
    if (lane < 16) h1[(size_t)n * 16 + h] = rv;   // 16 lanes x 4B = one full 64B line
}

// ---------------- fused layer-2: gather h1 directly (L2-resident, 1 line/edge),
// compute W2 product on the fly (W2t L1-resident), mean+root2+bias2+log_softmax ----------------
__global__ void k_agg2d(const int* __restrict__ rowStart, const uint4* __restrict__ rec,
                        const float* __restrict__ h1, const float* __restrict__ W2t,
                        const float* __restrict__ root2, const float* __restrict__ bias2,
                        float* __restrict__ out, int N) {
    int n = blockIdx.x * 4 + (threadIdx.x >> 6);
    if (n >= N) return;
    int lane = threadIdx.x & 63;
    int sub = lane >> 3, c = lane & 7;        // 8 edge-subgroups x 8 channels
    int start = rowStart[n], end = rowStart[n + 1];
    float acc = 0.0f;
    for (int i = start + sub; i < end; i += 8) {
        uint4 r = rec[i];
        float bt0 = bf2f((unsigned short)(r.x & 0xffffu));
        float bt1 = bf2f((unsigned short)(r.x >> 16));
        float bt2 = bf2f((unsigned short)(r.y & 0xffffu));
        float bt3 = bf2f((unsigned short)(r.y >> 16));
        int s = (int)r.z;
        unsigned w = r.w;
        // h1 row: 8 lanes read same 64B -> L1 broadcast; buffer is L2-resident (3.2MB)
        const float4* hp = (const float4*)(h1 + (size_t)s * 16);
        float4 h0 = hp[0], h1v = hp[1], h2 = hp[2], h3 = hp[3];
        float bts[4] = {bt0, bt1, bt2, bt3};
#pragma unroll
        for (int t = 0; t < 4; t++) {
            int wv = (int)((w >> (8 * t)) & 255u);
            const float4* wp = (const float4*)(W2t + ((size_t)(wv * 8 + c)) * 16);
            float4 a0 = wp[0], a1 = wp[1], a2 = wp[2], a3 = wp[3];
            float m = h0.x * a0.x + h0.y * a0.y + h0.z * a0.z + h0.w * a0.w
                    + h1v.x * a1.x + h1v.y * a1.y + h1v.z * a1.z + h1v.w * a1.w
                    + h2.x * a2.x + h2.y * a2.y + h2.z * a2.z + h2.w * a2.w
                    + h3.x * a3.x + h3.y * a3.y + h3.z * a3.z + h3.w * a3.w;
            acc += bts[t] * m;
        }
    }
    acc += __shfl_xor(acc, 8, 64);
    acc += __shfl_xor(acc, 16, 64);
    acc += __shfl_xor(acc, 32, 64);
    // every lane holds the total for its c (identical across subgroups)
    float inv = 1.0f / (float)max(end - start, 1);
    float z;
    if (c < CC) {
        z = acc * inv + bias2[c];
        const float* hrow = h1 + (size_t)n * 16;
#pragma unroll
        for (int i = 0; i < 16; i++) z += hrow[i] * root2[i * CC + c];
    } else {
        z = -1e30f;
    }
    float m = z;
    m = fmaxf(m, __shfl_xor(m, 1, 64));
    m = fmaxf(m, __shfl_xor(m, 2, 64));
    m = fmaxf(m, __shfl_xor(m, 4, 64));
    float ex = (c < CC) ? expf(z - m) : 0.0f;
    float ssum = ex;
    ssum += __shfl_xor(ssum, 1, 64);
    ssum += __shfl_xor(ssum, 2, 64);
    ssum += __shfl_xor(ssum, 4, 64);
    float ls = logf(ssum);
    if (lane < CC) out[(size_t)n * 7 + c] = z - m - ls;
}

extern "C" void kernel_launch(void* const* d_in, const int* in_sizes, int n_in,
                              void* d_out, int out_size, void* d_ws, size_t ws_size,
                              hipStream_t stream) {
    const float* x     = (const float*)d_in[0];
    const int*   ei    = (const int*)d_in[1];
    const float* attr  = (const float*)d_in[2];
    const float* W1    = (const float*)d_in[3];
    const float* root1 = (const float*)d_in[4];
    const float* bias1 = (const float*)d_in[5];
    const float* W2    = (const float*)d_in[6];
    const float* root2 = (const float*)d_in[7];
    const float* bias2 = (const float*)d_in[8];
    float* out = (float*)d_out;

    int N = in_sizes[0] / FIN;
    int E = in_sizes[1] / 2;

    char* w = (char*)d_ws;
    size_t off = 0;
    auto alloc = [&](size_t bytes) -> void* {
        void* p = w + off;
        off += (bytes + 255) & ~(size_t)255;
        return p;
    };
    int*      cnt      = (int*)alloc((size_t)N * 4);
    int*      rowStart = (int*)alloc((size_t)(N + 1) * 4);
    int*      cursor   = (int*)alloc((size_t)N * 4);
    int*      bsum     = (int*)alloc(260 * 4);
    int*      boff     = (int*)alloc(260 * 4);
    uint4*    rec      = (uint4*)alloc((size_t)E * 16);
    float*    h1       = (float*)alloc((size_t)N * 64);
    float*    B1t      = (float*)alloc((size_t)KK2 * FIN * HH * 4);
    float*    W2t      = (float*)alloc((size_t)KK2 * 8 * HH * 4);
    unsigned short* y1Tb = (unsigned short*)alloc((size_t)N * 400 * 2);
    (void)ws_size; (void)n_in; (void)out_size;

    hipMemsetAsync(cnt, 0, (size_t)N * 4, stream);

    int ebl = (E + 255) / 256;
    int nbl = (N + 255) / 256;
    int sblk = (N + SCAN_CHUNK - 1) / SCAN_CHUNK;   // 49 blocks for N=50k

    k_hist<<<ebl, 256, 0, stream>>>(ei, cnt, E);
    k_bsum<<<sblk, SCAN_BLK, 0, stream>>>(cnt, bsum, N);
    k_bscan<<<1, 256, 0, stream>>>(bsum, boff, sblk);
    k_sfin<<<sblk, SCAN_BLK, 0, stream>>>(cnt, boff, rowStart, cursor, N);
    k_scatter<<<ebl, 256, 0, stream>>>(attr, ei, cursor, rec, E);
    k_prepW<<<(KK2 * FIN * HH + 255) / 256, 256, 0, stream>>>(W1, W2, B1t, W2t);
    k_y1<<<KSPLIT * nbl, 256, 0, stream>>>(x, B1t, y1Tb, N, nbl);
    k_agg1u<<<(N + 3) / 4, 256, 0, stream>>>(rowStart, rec, y1Tb, x, root1, bias1, h1, N);
    k_agg2d<<<(N + 3) / 4, 256, 0, stream>>>(rowStart, rec, h1, W2t, root2, bias2, out, N);
}

// Round 17
// 289.221 us; speedup vs baseline: 1.2604x; 1.2604x over previous
//
#include <hip/hip_runtime.h>

#define KK2 25
#define FIN 64
#define HH 16
#define CC 7

#define SCAN_VPT 4
#define SCAN_BLK 256
#define SCAN_CHUNK (SCAN_VPT * SCAN_BLK)   // 1024 elements per block

__device__ inline unsigned short f2bf(float f) {   // RNE float->bf16
    unsigned u = __float_as_uint(f);
    return (unsigned short)((u + 0x7FFFu + ((u >> 16) & 1u)) >> 16);
}
__device__ inline float bf2f(unsigned short b) {   // exact bf16->float
    return __uint_as_float(((unsigned)b) << 16);
}

// ---------------- histogram of dst degrees (int atomics) ----------------
__global__ void k_hist(const int* __restrict__ ei, int* __restrict__ cnt, int E) {
    int e = blockIdx.x * 256 + threadIdx.x;
    if (e < E) atomicAdd(&cnt[ei[E + e]], 1);
}

// ---------------- scan pass 1: per-block sums ----------------
__global__ void k_bsum(const int* __restrict__ cnt, int* __restrict__ bsum, int N) {
    int b = blockIdx.x, t = threadIdx.x;
    int base = b * SCAN_CHUNK + t * SCAN_VPT;
    int s = 0;
#pragma unroll
    for (int j = 0; j < SCAN_VPT; j++) {
        int i = base + j;
        if (i < N) s += cnt[i];
    }
#pragma unroll
    for (int d = 1; d < 64; d <<= 1) s += __shfl_xor(s, d, 64);
    __shared__ int sd[SCAN_BLK / 64];
    if ((t & 63) == 0) sd[t >> 6] = s;
    __syncthreads();
    if (t == 0) {
        int tot = 0;
        for (int w = 0; w < SCAN_BLK / 64; w++) tot += sd[w];
        bsum[b] = tot;
    }
}

// ---------------- scan pass 2: scan the block sums (single small block) ----------------
__global__ void k_bscan(const int* __restrict__ bsum, int* __restrict__ boff, int nblk) {
    int t = threadIdx.x;            // 256 threads, nblk <= 256
    __shared__ int sd[256];
    int v = (t < nblk) ? bsum[t] : 0;
    sd[t] = v;
    __syncthreads();
    for (int off = 1; off < 256; off <<= 1) {
        int u = (t >= off) ? sd[t - off] : 0;
        __syncthreads();
        sd[t] += u;
        __syncthreads();
    }
    boff[t] = sd[t] - v;            // exclusive prefix
}

// ---------------- scan pass 3: local scan + block offset -> rowStart, cursor ----------------
__global__ void k_sfin(const int* __restrict__ cnt, const int* __restrict__ boff,
                       int* __restrict__ rowStart, int* __restrict__ cursor, int N) {
    int b = blockIdx.x, t = threadIdx.x;
    int base = b * SCAN_CHUNK + t * SCAN_VPT;
    int v[SCAN_VPT];
    int s = 0;
#pragma unroll
    for (int j = 0; j < SCAN_VPT; j++) {
        int i = base + j;
        v[j] = (i < N) ? cnt[i] : 0;
        s += v[j];
    }
    __shared__ int sd[SCAN_BLK];
    sd[t] = s;
    __syncthreads();
    for (int off = 1; off < SCAN_BLK; off <<= 1) {
        int u = (t >= off) ? sd[t - off] : 0;
        __syncthreads();
        sd[t] += u;
        __syncthreads();
    }
    int run = sd[t] - s + boff[b];
#pragma unroll
    for (int j = 0; j < SCAN_VPT; j++) {
        int i = base + j;
        if (i < N) {
            rowStart[i] = run;
            cursor[i] = run;
            run += v[j];
            if (i == N - 1) rowStart[N] = run;
        }
    }
}

// ---------------- scatter edges into dst-sorted order, packed 16B records ----------------
// rec[pos] = {bf16 b.x|b.y, bf16 b.z|b.w, src, pA | pB<<8}
// pA = i0a*5+i1a (pair-plane for terms x,z), pB = i0b*5+i1a (terms y,w)
__global__ void k_scatter(const float* __restrict__ attr, const int* __restrict__ ei,
                          int* __restrict__ cursor, uint4* __restrict__ rec, int E) {
    int e = blockIdx.x * 256 + threadIdx.x;
    if (e >= E) return;
    float v0 = attr[2 * e] * 4.0f, v1 = attr[2 * e + 1] * 4.0f;
    float l0 = floorf(v0), l1 = floorf(v1);
    float f0 = v0 - l0, f1 = v1 - l1;
    int i0 = (int)l0, i1 = (int)l1;
    int i0a = min(max(i0, 0), 4), i0b = min(max(i0 + 1, 0), 4);
    int i1a = min(max(i1, 0), 4);
    float bx = (1.0f - f0) * (1.0f - f1);
    float by = f0 * (1.0f - f1);
    float bz = (1.0f - f0) * f1;
    float bw = f0 * f1;
    unsigned pA = (unsigned)(i0a * 5 + i1a);
    unsigned pB = (unsigned)(i0b * 5 + i1a);
    int s = ei[e], d = ei[E + e];
    int pos = atomicAdd(&cursor[d], 1);
    uint4 r;
    r.x = (unsigned)f2bf(bx) | ((unsigned)f2bf(by) << 16);
    r.y = (unsigned)f2bf(bz) | ((unsigned)f2bf(bw) << 16);
    r.z = (unsigned)s;
    r.w = pA | (pB << 8);
    rec[pos] = r;
}

// ---------------- repack weights: B1t for k_y1, W2p (zero-padded) for k_y2 ----------------
__global__ void k_prepW(const float* __restrict__ W1, const float* __restrict__ W2,
                        float* __restrict__ B1t, float* __restrict__ W2p) {
    int tid = blockIdx.x * 256 + threadIdx.x;
    if (tid < KK2 * FIN * HH) {
        int c = tid >> 6, i = tid & 63;
        int k = c >> 4, h = c & 15;
        B1t[tid] = W1[(k * FIN + i) * HH + h];
    }
    if (tid < KK2 * HH * 8) {
        int k = tid >> 7, r = tid & 127;
        int i = r >> 3, c = r & 7;
        W2p[tid] = (c < CC) ? W2[(k * HH + i) * CC + c] : 0.0f;
    }
}

// ---------------- y1q[(i0*5+i1a)][n][32] bf16 pair-planes ----------------
// Row = 64B = [h(i0,i1a) | h(i0,min(i1a+1,4))]. Block owns one i0 (all 5 i1),
// double-buffers each i1's 2KB in LDS, drains pair-rows lane-contiguous 4KB
// (full 64B lines -> amp 1.0, r8-verified pattern).
__global__ void k_y1(const float* __restrict__ x, const float* __restrict__ B1t,
                     unsigned short* __restrict__ y1q, int N, int nbl) {
    __shared__ uint4 sh[4][2][144];          // [wave][slot][128 + pad]
    int i0 = blockIdx.x / nbl;               // 0..4, block-uniform
    int nwin = blockIdx.x % nbl;
    int n = nwin * 256 + threadIdx.x;
    int wv = threadIdx.x >> 6, lane = threadIdx.x & 63;
    bool active = (n < N);
    float4 xr[16];
    if (active) {
        const float4* xp = (const float4*)(x + (size_t)n * 64);
#pragma unroll
        for (int i = 0; i < 16; i++) xr[i] = xp[i];
    }
    int nwb = nwin * 256 + wv * 64;          // wave's base node
    int validf = min(64, max(0, N - nwb)) * 4;   // valid 16B elems in 4KB drain
    size_t NN = (size_t)N;

    for (int i1 = 0; i1 < 5; i1++) {
        int k = i0 * 5 + i1;
        const float* B = B1t + k * 16 * 64;  // 4KB, L1-resident, block-uniform
        unsigned tmp[8];
        if (active) {
#pragma unroll
            for (int h4 = 0; h4 < 4; h4++) {
                float a0 = 0, a1 = 0, a2 = 0, a3 = 0;
                const float4* b0 = (const float4*)(B + (h4 * 4 + 0) * 64);
                const float4* b1 = (const float4*)(B + (h4 * 4 + 1) * 64);
                const float4* b2 = (const float4*)(B + (h4 * 4 + 2) * 64);
                const float4* b3 = (const float4*)(B + (h4 * 4 + 3) * 64);
#pragma unroll
                for (int i = 0; i < 16; i++) {
                    float4 xi = xr[i];
                    float4 v0 = b0[i], v1 = b1[i], v2 = b2[i], v3 = b3[i];
                    a0 += xi.x * v0.x + xi.y * v0.y + xi.z * v0.z + xi.w * v0.w;
                    a1 += xi.x * v1.x + xi.y * v1.y + xi.z * v1.z + xi.w * v1.w;
                    a2 += xi.x * v2.x + xi.y * v2.y + xi.z * v2.z + xi.w * v2.w;
                    a3 += xi.x * v3.x + xi.y * v3.y + xi.z * v3.z + xi.w * v3.w;
                }
                tmp[h4 * 2 + 0] = (unsigned)f2bf(a0) | ((unsigned)f2bf(a1) << 16);
                tmp[h4 * 2 + 1] = (unsigned)f2bf(a2) | ((unsigned)f2bf(a3) << 16);
            }
        } else {
#pragma unroll
            for (int j = 0; j < 8; j++) tmp[j] = 0;
        }
        int slot = i1 & 1;
        int i0e = lane * 2, i1e = lane * 2 + 1;
        sh[wv][slot][i0e + (i0e >> 3)] = make_uint4(tmp[0], tmp[1], tmp[2], tmp[3]);
        sh[wv][slot][i1e + (i1e >> 3)] = make_uint4(tmp[4], tmp[5], tmp[6], tmp[7]);
        __syncthreads();
        // drain pair-plane (i0, i1-1): first half from slot^1 (k=i1-1), second from slot (k=i1)
        if (i1 >= 1) {
            int p = i0 * 5 + (i1 - 1);
            uint4* g4 = (uint4*)(y1q + ((size_t)p * NN + nwb) * 32);
#pragma unroll
            for (int j = 0; j < 4; j++) {
                int f = j * 64 + lane;
                if (f < validf) {
                    int node = f >> 2, piece = f & 3;
                    int idx = node * 2 + (piece & 1);
                    int ss = (piece < 2) ? (slot ^ 1) : slot;
                    g4[f] = sh[wv][ss][idx + (idx >> 3)];
                }
            }
        }
        // last plane (i0,4): both halves from k=4 (i1b clamps to 4)
        if (i1 == 4) {
            int p = i0 * 5 + 4;
            uint4* g4 = (uint4*)(y1q + ((size_t)p * NN + nwb) * 32);
#pragma unroll
            for (int j = 0; j < 4; j++) {
                int f = j * 64 + lane;
                if (f < validf) {
                    int node = f >> 2, piece = f & 3;
                    int idx = node * 2 + (piece & 1);
                    g4[f] = sh[wv][slot][idx + (idx >> 3)];
                }
            }
        }
        __syncthreads();
    }
}

// ---------------- fused layer-1: 2-line pair-plane gather + mean + root1 + bias1 + relu ----------------
__global__ void k_agg1u(const int* __restrict__ rowStart, const uint4* __restrict__ rec,
                        const unsigned short* __restrict__ y1q, const float* __restrict__ x,
                        const float* __restrict__ root1, const float* __restrict__ bias1,
                        float* __restrict__ h1, int N) {
    int n = blockIdx.x * 4 + (threadIdx.x >> 6);
    if (n >= N) return;
    int lane = threadIdx.x & 63;
    int sub = lane >> 4, h = lane & 15;
    int start = rowStart[n], end = rowStart[n + 1];
    float acc = 0.0f;
    size_t NN = (size_t)N;
    for (int i = start + sub; i < end; i += 4) {
        uint4 r = rec[i];
        float bx = bf2f((unsigned short)(r.x & 0xffffu));
        float by = bf2f((unsigned short)(r.x >> 16));
        float bz = bf2f((unsigned short)(r.y & 0xffffu));
        float bw = bf2f((unsigned short)(r.y >> 16));
        int s = (int)r.z;
        unsigned w = r.w;
        const unsigned short* rA = y1q + ((w & 255u) * NN + s) * 32;
        const unsigned short* rB = y1q + (((w >> 8) & 255u) * NN + s) * 32;
        acc += bx * bf2f(rA[h]) + bz * bf2f(rA[16 + h]);
        acc += by * bf2f(rB[h]) + bw * bf2f(rB[16 + h]);
    }
    acc += __shfl_xor(acc, 16, 64);
    acc += __shfl_xor(acc, 32, 64);
    float inv = 1.0f / (float)max(end - start, 1);
    float rv = acc * inv + bias1[h];
    const float* xrow = x + (size_t)n * 64;
#pragma unroll 8
    for (int i = 0; i < 64; i++) rv += xrow[i] * root1[i * 16 + h];
    rv = fmaxf(rv, 0.0f);
    if (lane < 16) h1[(size_t)n * 16 + h] = rv;   // one full 64B line
}

// ---------------- y2T[k][n][8] bf16 = (h1 @ W2[k])[n], kg-parallel (r15-verified) ----------------
__global__ void k_y2(const float* __restrict__ h1, const float* __restrict__ W2p,
                     unsigned short* __restrict__ y2Tb, int N, int nbl) {
    int kg = blockIdx.x / nbl;               // 0..4, block-uniform
    int n = (blockIdx.x % nbl) * 256 + threadIdx.x;
    if (n >= N) return;
    float hreg[16];
    const float4* hp = (const float4*)(h1 + (size_t)n * 16);
#pragma unroll
    for (int j = 0; j < 4; j++) {
        float4 v = hp[j];
        hreg[4 * j] = v.x; hreg[4 * j + 1] = v.y;
        hreg[4 * j + 2] = v.z; hreg[4 * j + 3] = v.w;
    }
#pragma unroll
    for (int dk = 0; dk < 5; dk++) {
        int k = kg * 5 + dk;
        float z[8] = {0, 0, 0, 0, 0, 0, 0, 0};
        const float4* wp = (const float4*)(W2p + k * 128);  // 512B, L1-resident
#pragma unroll
        for (int i = 0; i < 16; i++) {
            float hi = hreg[i];
            float4 lo = wp[2 * i], hv = wp[2 * i + 1];
            z[0] += hi * lo.x; z[1] += hi * lo.y; z[2] += hi * lo.z; z[3] += hi * lo.w;
            z[4] += hi * hv.x; z[5] += hi * hv.y; z[6] += hi * hv.z; z[7] += hi * hv.w;
        }
        uint4 p;
        p.x = (unsigned)f2bf(z[0]) | ((unsigned)f2bf(z[1]) << 16);
        p.y = (unsigned)f2bf(z[2]) | ((unsigned)f2bf(z[3]) << 16);
        p.z = (unsigned)f2bf(z[4]) | ((unsigned)f2bf(z[5]) << 16);
        p.w = (unsigned)f2bf(z[6]) | ((unsigned)f2bf(z[7]) << 16);
        *(uint4*)(y2Tb + ((size_t)k * N + n) * 8) = p;   // lane-contiguous, full lines
    }
}

// ---------------- fused layer-2: gather + mean + root2 + bias2 + log_softmax -> out ----------------
// k-indices recovered from pair-plane ids: k00=pA, k10=pB, k01=pA+d, k11=pB+d, d=(pA%5<4)
__global__ void k_agg2f(const int* __restrict__ rowStart, const uint4* __restrict__ rec,
                        const unsigned short* __restrict__ y2Tb, const float* __restrict__ h1,
                        const float* __restrict__ root2, const float* __restrict__ bias2,
                        float* __restrict__ out, int N) {
    int n = blockIdx.x * 4 + (threadIdx.x >> 6);
    if (n >= N) return;
    int lane = threadIdx.x & 63;
    int sub = lane >> 3, c = lane & 7;        // 8 edge-subgroups x 8 channels
    int start = rowStart[n], end = rowStart[n + 1];
    float acc = 0.0f;
    size_t NN = (size_t)N;
    for (int i = start + sub; i < end; i += 8) {
        uint4 r = rec[i];
        float bx = bf2f((unsigned short)(r.x & 0xffffu));
        float by = bf2f((unsigned short)(r.x >> 16));
        float bz = bf2f((unsigned short)(r.y & 0xffffu));
        float bw = bf2f((unsigned short)(r.y >> 16));
        int s = (int)r.z;
        unsigned pA = r.w & 255u, pB = (r.w >> 8) & 255u;
        unsigned i1a = pA % 5u;
        unsigned d = (i1a < 4u) ? 1u : 0u;
        acc += bx * bf2f(y2Tb[(pA * NN + s) * 8 + c]);
        acc += by * bf2f(y2Tb[(pB * NN + s) * 8 + c]);
        acc += bz * bf2f(y2Tb[((pA + d) * NN + s) * 8 + c]);
        acc += bw * bf2f(y2Tb[((pB + d) * NN + s) * 8 + c]);
    }
    acc += __shfl_xor(acc, 8, 64);
    acc += __shfl_xor(acc, 16, 64);
    acc += __shfl_xor(acc, 32, 64);
    float inv = 1.0f / (float)max(end - start, 1);
    float z;
    if (c < CC) {
        z = acc * inv + bias2[c];
        const float* hrow = h1 + (size_t)n * 16;
#pragma unroll
        for (int i = 0; i < 16; i++) z += hrow[i] * root2[i * CC + c];
    } else {
        z = -1e30f;
    }
    float m = z;
    m = fmaxf(m, __shfl_xor(m, 1, 64));
    m = fmaxf(m, __shfl_xor(m, 2, 64));
    m = fmaxf(m, __shfl_xor(m, 4, 64));
    float ex = (c < CC) ? expf(z - m) : 0.0f;
    float ssum = ex;
    ssum += __shfl_xor(ssum, 1, 64);
    ssum += __shfl_xor(ssum, 2, 64);
    ssum += __shfl_xor(ssum, 4, 64);
    float ls = logf(ssum);
    if (lane < CC) out[(size_t)n * 7 + c] = z - m - ls;
}

extern "C" void kernel_launch(void* const* d_in, const int* in_sizes, int n_in,
                              void* d_out, int out_size, void* d_ws, size_t ws_size,
                              hipStream_t stream) {
    const float* x     = (const float*)d_in[0];
    const int*   ei    = (const int*)d_in[1];
    const float* attr  = (const float*)d_in[2];
    const float* W1    = (const float*)d_in[3];
    const float* root1 = (const float*)d_in[4];
    const float* bias1 = (const float*)d_in[5];
    const float* W2    = (const float*)d_in[6];
    const float* root2 = (const float*)d_in[7];
    const float* bias2 = (const float*)d_in[8];
    float* out = (float*)d_out;

    int N = in_sizes[0] / FIN;
    int E = in_sizes[1] / 2;

    char* w = (char*)d_ws;
    size_t off = 0;
    auto alloc = [&](size_t bytes) -> void* {
        void* p = w + off;
        off += (bytes + 255) & ~(size_t)255;
        return p;
    };
    int*      cnt      = (int*)alloc((size_t)N * 4);
    int*      rowStart = (int*)alloc((size_t)(N + 1) * 4);
    int*      cursor   = (int*)alloc((size_t)N * 4);
    int*      bsum     = (int*)alloc(260 * 4);
    int*      boff     = (int*)alloc(260 * 4);
    uint4*    rec      = (uint4*)alloc((size_t)E * 16);
    float*    h1       = (float*)alloc((size_t)N * 64);
    float*    B1t      = (float*)alloc((size_t)KK2 * FIN * HH * 4);
    float*    W2p      = (float*)alloc((size_t)KK2 * HH * 8 * 4);
    unsigned short* y1q  = (unsigned short*)alloc((size_t)KK2 * N * 32 * 2);  // 80MB pair-planes
    unsigned short* y2Tb = y1q;   // alias: y1q dead after k_agg1u; y2Tb is [25][N][8]
    (void)ws_size; (void)n_in; (void)out_size;

    hipMemsetAsync(cnt, 0, (size_t)N * 4, stream);

    int ebl = (E + 255) / 256;
    int nbl = (N + 255) / 256;
    int sblk = (N + SCAN_CHUNK - 1) / SCAN_CHUNK;   // 49 blocks for N=50k

    k_hist<<<ebl, 256, 0, stream>>>(ei, cnt, E);
    k_bsum<<<sblk, SCAN_BLK, 0, stream>>>(cnt, bsum, N);
    k_bscan<<<1, 256, 0, stream>>>(bsum, boff, sblk);
    k_sfin<<<sblk, SCAN_BLK, 0, stream>>>(cnt, boff, rowStart, cursor, N);
    k_scatter<<<ebl, 256, 0, stream>>>(attr, ei, cursor, rec, E);
    k_prepW<<<(KK2 * FIN * HH + 255) / 256, 256, 0, stream>>>(W1, W2, B1t, W2p);
    k_y1<<<5 * nbl, 256, 0, stream>>>(x, B1t, y1q, N, nbl);
    k_agg1u<<<(N + 3) / 4, 256, 0, stream>>>(rowStart, rec, y1q, x, root1, bias1, h1, N);
    k_y2<<<5 * nbl, 256, 0, stream>>>(h1, W2p, y2Tb, N, nbl);
    k_agg2f<<<(N + 3) / 4, 256, 0, stream>>>(rowStart, rec, y2Tb, h1, root2, bias2, out, N);
}

// Round 18
// 286.747 us; speedup vs baseline: 1.2712x; 1.0086x over previous
//
#include <hip/hip_runtime.h>

#define KK2 25
#define FIN 64
#define HH 16
#define CC 7

#define SCAN_VPT 4
#define SCAN_BLK 256
#define SCAN_CHUNK (SCAN_VPT * SCAN_BLK)   // 1024 elements per block

__device__ inline unsigned short f2bf(float f) {   // RNE float->bf16
    unsigned u = __float_as_uint(f);
    return (unsigned short)((u + 0x7FFFu + ((u >> 16) & 1u)) >> 16);
}
__device__ inline float bf2f(unsigned short b) {   // exact bf16->float
    return __uint_as_float(((unsigned)b) << 16);
}

// ---------------- histogram of dst degrees (int atomics) ----------------
__global__ void k_hist(const int* __restrict__ ei, int* __restrict__ cnt, int E) {
    int e = blockIdx.x * 256 + threadIdx.x;
    if (e < E) atomicAdd(&cnt[ei[E + e]], 1);
}

// ---------------- scan pass 1: per-block sums ----------------
__global__ void k_bsum(const int* __restrict__ cnt, int* __restrict__ bsum, int N) {
    int b = blockIdx.x, t = threadIdx.x;
    int base = b * SCAN_CHUNK + t * SCAN_VPT;
    int s = 0;
#pragma unroll
    for (int j = 0; j < SCAN_VPT; j++) {
        int i = base + j;
        if (i < N) s += cnt[i];
    }
#pragma unroll
    for (int d = 1; d < 64; d <<= 1) s += __shfl_xor(s, d, 64);
    __shared__ int sd[SCAN_BLK / 64];
    if ((t & 63) == 0) sd[t >> 6] = s;
    __syncthreads();
    if (t == 0) {
        int tot = 0;
        for (int w = 0; w < SCAN_BLK / 64; w++) tot += sd[w];
        bsum[b] = tot;
    }
}

// ---------------- scan pass 2: scan the block sums (single small block) ----------------
__global__ void k_bscan(const int* __restrict__ bsum, int* __restrict__ boff, int nblk) {
    int t = threadIdx.x;            // 256 threads, nblk <= 256
    __shared__ int sd[256];
    int v = (t < nblk) ? bsum[t] : 0;
    sd[t] = v;
    __syncthreads();
    for (int off = 1; off < 256; off <<= 1) {
        int u = (t >= off) ? sd[t - off] : 0;
        __syncthreads();
        sd[t] += u;
        __syncthreads();
    }
    boff[t] = sd[t] - v;            // exclusive prefix
}

// ---------------- scan pass 3: local scan + block offset -> rowStart, cursor ----------------
__global__ void k_sfin(const int* __restrict__ cnt, const int* __restrict__ boff,
                       int* __restrict__ rowStart, int* __restrict__ cursor, int N) {
    int b = blockIdx.x, t = threadIdx.x;
    int base = b * SCAN_CHUNK + t * SCAN_VPT;
    int v[SCAN_VPT];
    int s = 0;
#pragma unroll
    for (int j = 0; j < SCAN_VPT; j++) {
        int i = base + j;
        v[j] = (i < N) ? cnt[i] : 0;
        s += v[j];
    }
    __shared__ int sd[SCAN_BLK];
    sd[t] = s;
    __syncthreads();
    for (int off = 1; off < SCAN_BLK; off <<= 1) {
        int u = (t >= off) ? sd[t - off] : 0;
        __syncthreads();
        sd[t] += u;
        __syncthreads();
    }
    int run = sd[t] - s + boff[b];
#pragma unroll
    for (int j = 0; j < SCAN_VPT; j++) {
        int i = base + j;
        if (i < N) {
            rowStart[i] = run;
            cursor[i] = run;
            run += v[j];
            if (i == N - 1) rowStart[N] = run;
        }
    }
}

// ---------------- scatter edges into dst-sorted order, packed 16B records ----------------
// rec[pos] = {bf16 b.x|b.y, bf16 b.z|b.w, src, pA | pB<<8}
// pA = i0a*5+i1a (pair-plane for terms x,z), pB = i0b*5+i1a (terms y,w)
__global__ void k_scatter(const float* __restrict__ attr, const int* __restrict__ ei,
                          int* __restrict__ cursor, uint4* __restrict__ rec, int E) {
    int e = blockIdx.x * 256 + threadIdx.x;
    if (e >= E) return;
    float v0 = attr[2 * e] * 4.0f, v1 = attr[2 * e + 1] * 4.0f;
    float l0 = floorf(v0), l1 = floorf(v1);
    float f0 = v0 - l0, f1 = v1 - l1;
    int i0 = (int)l0, i1 = (int)l1;
    int i0a = min(max(i0, 0), 4), i0b = min(max(i0 + 1, 0), 4);
    int i1a = min(max(i1, 0), 4);
    float bx = (1.0f - f0) * (1.0f - f1);
    float by = f0 * (1.0f - f1);
    float bz = (1.0f - f0) * f1;
    float bw = f0 * f1;
    unsigned pA = (unsigned)(i0a * 5 + i1a);
    unsigned pB = (unsigned)(i0b * 5 + i1a);
    int s = ei[e], d = ei[E + e];
    int pos = atomicAdd(&cursor[d], 1);
    uint4 r;
    r.x = (unsigned)f2bf(bx) | ((unsigned)f2bf(by) << 16);
    r.y = (unsigned)f2bf(bz) | ((unsigned)f2bf(bw) << 16);
    r.z = (unsigned)s;
    r.w = pA | (pB << 8);
    rec[pos] = r;
}

// ---------------- repack weights: B1t for k_y1, W2p (zero-padded) for k_y2 ----------------
__global__ void k_prepW(const float* __restrict__ W1, const float* __restrict__ W2,
                        float* __restrict__ B1t, float* __restrict__ W2p) {
    int tid = blockIdx.x * 256 + threadIdx.x;
    if (tid < KK2 * FIN * HH) {
        int c = tid >> 6, i = tid & 63;
        int k = c >> 4, h = c & 15;
        B1t[tid] = W1[(k * FIN + i) * HH + h];
    }
    if (tid < KK2 * HH * 8) {
        int k = tid >> 7, r = tid & 127;
        int i = r >> 3, c = r & 7;
        W2p[tid] = (c < CC) ? W2[(k * HH + i) * CC + c] : 0.0f;
    }
}

// ---------------- y1n[n][p][32] bf16, n-major pair-rows (1600B per node) ----------------
// Pair-row p = i0*5+i1a: 64B = [h(i0,i1a) | h(i0,min(i1a+1,4))]. An edge's two
// rows (pA,pB) sit in one node's 1600B span -> same DRAM page on gather.
// Drain: each store instr = 16 FULL 64B-aligned lines (4 lanes/line, 1600B stride).
__global__ void k_y1(const float* __restrict__ x, const float* __restrict__ B1t,
                     unsigned short* __restrict__ y1n, int N, int nbl) {
    __shared__ uint4 sh[4][2][144];          // [wave][slot][128 + pad]
    int i0 = blockIdx.x / nbl;               // 0..4, block-uniform
    int nwin = blockIdx.x % nbl;
    int n = nwin * 256 + threadIdx.x;
    int wv = threadIdx.x >> 6, lane = threadIdx.x & 63;
    bool active = (n < N);
    float4 xr[16];
    if (active) {
        const float4* xp = (const float4*)(x + (size_t)n * 64);
#pragma unroll
        for (int i = 0; i < 16; i++) xr[i] = xp[i];
    }
    int nwb = nwin * 256 + wv * 64;          // wave's base node
    int validf = min(64, max(0, N - nwb)) * 4;   // valid 16B pieces in wave's drain

    for (int i1 = 0; i1 < 5; i1++) {
        int k = i0 * 5 + i1;
        const float* B = B1t + k * 16 * 64;  // 4KB, L1-resident, block-uniform
        unsigned tmp[8];
        if (active) {
#pragma unroll
            for (int h4 = 0; h4 < 4; h4++) {
                float a0 = 0, a1 = 0, a2 = 0, a3 = 0;
                const float4* b0 = (const float4*)(B + (h4 * 4 + 0) * 64);
                const float4* b1 = (const float4*)(B + (h4 * 4 + 1) * 64);
                const float4* b2 = (const float4*)(B + (h4 * 4 + 2) * 64);
                const float4* b3 = (const float4*)(B + (h4 * 4 + 3) * 64);
#pragma unroll
                for (int i = 0; i < 16; i++) {
                    float4 xi = xr[i];
                    float4 v0 = b0[i], v1 = b1[i], v2 = b2[i], v3 = b3[i];
                    a0 += xi.x * v0.x + xi.y * v0.y + xi.z * v0.z + xi.w * v0.w;
                    a1 += xi.x * v1.x + xi.y * v1.y + xi.z * v1.z + xi.w * v1.w;
                    a2 += xi.x * v2.x + xi.y * v2.y + xi.z * v2.z + xi.w * v2.w;
                    a3 += xi.x * v3.x + xi.y * v3.y + xi.z * v3.z + xi.w * v3.w;
                }
                tmp[h4 * 2 + 0] = (unsigned)f2bf(a0) | ((unsigned)f2bf(a1) << 16);
                tmp[h4 * 2 + 1] = (unsigned)f2bf(a2) | ((unsigned)f2bf(a3) << 16);
            }
        } else {
#pragma unroll
            for (int j = 0; j < 8; j++) tmp[j] = 0;
        }
        int slot = i1 & 1;
        int i0e = lane * 2, i1e = lane * 2 + 1;
        sh[wv][slot][i0e + (i0e >> 3)] = make_uint4(tmp[0], tmp[1], tmp[2], tmp[3]);
        sh[wv][slot][i1e + (i1e >> 3)] = make_uint4(tmp[4], tmp[5], tmp[6], tmp[7]);
        __syncthreads();
        // drain pair-plane (i0, i1-1): halves from slot^1 (k-1) and slot (k)
        if (i1 >= 1) {
            int p = i0 * 5 + (i1 - 1);
            uint4* g4 = (uint4*)y1n;         // 1600B/node = 100 uint4
#pragma unroll
            for (int j = 0; j < 4; j++) {
                int f = j * 64 + lane;
                if (f < validf) {
                    int m = f >> 2, q = f & 3;
                    int idx = m * 2 + (q & 1);
                    int ss = (q < 2) ? (slot ^ 1) : slot;
                    g4[(size_t)(nwb + m) * 100 + p * 4 + q] = sh[wv][ss][idx + (idx >> 3)];
                }
            }
        }
        // last plane (i0,4): both halves from k=4 (i1b clamps to 4)
        if (i1 == 4) {
            int p = i0 * 5 + 4;
            uint4* g4 = (uint4*)y1n;
#pragma unroll
            for (int j = 0; j < 4; j++) {
                int f = j * 64 + lane;
                if (f < validf) {
                    int m = f >> 2, q = f & 3;
                    int idx = m * 2 + (q & 1);
                    g4[(size_t)(nwb + m) * 100 + p * 4 + q] = sh[wv][slot][idx + (idx >> 3)];
                }
            }
        }
        __syncthreads();
    }
}

// ---------------- fused layer-1: n-major 2-line gather + mean + root1 + bias1 + relu ----------------
__global__ void k_agg1u(const int* __restrict__ rowStart, const uint4* __restrict__ rec,
                        const unsigned short* __restrict__ y1n, const float* __restrict__ x,
                        const float* __restrict__ root1, const float* __restrict__ bias1,
                        float* __restrict__ h1, int N) {
    int n = blockIdx.x * 4 + (threadIdx.x >> 6);
    if (n >= N) return;
    int lane = threadIdx.x & 63;
    int sub = lane >> 4, h = lane & 15;
    int start = rowStart[n], end = rowStart[n + 1];
    float acc0 = 0.0f, acc1 = 0.0f;
    int i = start + sub;
    // unroll-2: 8 edges in flight per wave (dual independent chains)
    for (; i + 4 < end; i += 8) {
        uint4 r0 = rec[i];
        uint4 r1 = rec[i + 4];
        {
            int s = (int)r0.z;
            unsigned w = r0.w;
            const unsigned short* rA = y1n + (size_t)s * 800 + (w & 255u) * 32;
            const unsigned short* rB = y1n + (size_t)s * 800 + ((w >> 8) & 255u) * 32;
            acc0 += bf2f((unsigned short)(r0.x & 0xffffu)) * bf2f(rA[h])
                  + bf2f((unsigned short)(r0.y & 0xffffu)) * bf2f(rA[16 + h])
                  + bf2f((unsigned short)(r0.x >> 16)) * bf2f(rB[h])
                  + bf2f((unsigned short)(r0.y >> 16)) * bf2f(rB[16 + h]);
        }
        {
            int s = (int)r1.z;
            unsigned w = r1.w;
            const unsigned short* rA = y1n + (size_t)s * 800 + (w & 255u) * 32;
            const unsigned short* rB = y1n + (size_t)s * 800 + ((w >> 8) & 255u) * 32;
            acc1 += bf2f((unsigned short)(r1.x & 0xffffu)) * bf2f(rA[h])
                  + bf2f((unsigned short)(r1.y & 0xffffu)) * bf2f(rA[16 + h])
                  + bf2f((unsigned short)(r1.x >> 16)) * bf2f(rB[h])
                  + bf2f((unsigned short)(r1.y >> 16)) * bf2f(rB[16 + h]);
        }
    }
    for (; i < end; i += 4) {
        uint4 r = rec[i];
        int s = (int)r.z;
        unsigned w = r.w;
        const unsigned short* rA = y1n + (size_t)s * 800 + (w & 255u) * 32;
        const unsigned short* rB = y1n + (size_t)s * 800 + ((w >> 8) & 255u) * 32;
        acc0 += bf2f((unsigned short)(r.x & 0xffffu)) * bf2f(rA[h])
              + bf2f((unsigned short)(r.y & 0xffffu)) * bf2f(rA[16 + h])
              + bf2f((unsigned short)(r.x >> 16)) * bf2f(rB[h])
              + bf2f((unsigned short)(r.y >> 16)) * bf2f(rB[16 + h]);
    }
    float acc = acc0 + acc1;
    acc += __shfl_xor(acc, 16, 64);
    acc += __shfl_xor(acc, 32, 64);
    float inv = 1.0f / (float)max(end - start, 1);
    float rv = acc * inv + bias1[h];
    const float* xrow = x + (size_t)n * 64;
#pragma unroll 8
    for (int ii = 0; ii < 64; ii++) rv += xrow[ii] * root1[ii * 16 + h];
    rv = fmaxf(rv, 0.0f);
    if (lane < 16) h1[(size_t)n * 16 + h] = rv;   // one full 64B line
}

// ---------------- y2T[k][n][8] bf16 = (h1 @ W2[k])[n], kg-parallel (r15-verified) ----------------
__global__ void k_y2(const float* __restrict__ h1, const float* __restrict__ W2p,
                     unsigned short* __restrict__ y2Tb, int N, int nbl) {
    int kg = blockIdx.x / nbl;               // 0..4, block-uniform
    int n = (blockIdx.x % nbl) * 256 + threadIdx.x;
    if (n >= N) return;
    float hreg[16];
    const float4* hp = (const float4*)(h1 + (size_t)n * 16);
#pragma unroll
    for (int j = 0; j < 4; j++) {
        float4 v = hp[j];
        hreg[4 * j] = v.x; hreg[4 * j + 1] = v.y;
        hreg[4 * j + 2] = v.z; hreg[4 * j + 3] = v.w;
    }
#pragma unroll
    for (int dk = 0; dk < 5; dk++) {
        int k = kg * 5 + dk;
        float z[8] = {0, 0, 0, 0, 0, 0, 0, 0};
        const float4* wp = (const float4*)(W2p + k * 128);  // 512B, L1-resident
#pragma unroll
        for (int i = 0; i < 16; i++) {
            float hi = hreg[i];
            float4 lo = wp[2 * i], hv = wp[2 * i + 1];
            z[0] += hi * lo.x; z[1] += hi * lo.y; z[2] += hi * lo.z; z[3] += hi * lo.w;
            z[4] += hi * hv.x; z[5] += hi * hv.y; z[6] += hi * hv.z; z[7] += hi * hv.w;
        }
        uint4 p;
        p.x = (unsigned)f2bf(z[0]) | ((unsigned)f2bf(z[1]) << 16);
        p.y = (unsigned)f2bf(z[2]) | ((unsigned)f2bf(z[3]) << 16);
        p.z = (unsigned)f2bf(z[4]) | ((unsigned)f2bf(z[5]) << 16);
        p.w = (unsigned)f2bf(z[6]) | ((unsigned)f2bf(z[7]) << 16);
        *(uint4*)(y2Tb + ((size_t)k * N + n) * 8) = p;   // lane-contiguous, full lines
    }
}

// ---------------- fused layer-2: gather + mean + root2 + bias2 + log_softmax -> out ----------------
// k-indices recovered from pair-plane ids: k00=pA, k10=pB, k01=pA+d, k11=pB+d, d=(pA%5<4)
__global__ void k_agg2f(const int* __restrict__ rowStart, const uint4* __restrict__ rec,
                        const unsigned short* __restrict__ y2Tb, const float* __restrict__ h1,
                        const float* __restrict__ root2, const float* __restrict__ bias2,
                        float* __restrict__ out, int N) {
    int n = blockIdx.x * 4 + (threadIdx.x >> 6);
    if (n >= N) return;
    int lane = threadIdx.x & 63;
    int sub = lane >> 3, c = lane & 7;        // 8 edge-subgroups x 8 channels
    int start = rowStart[n], end = rowStart[n + 1];
    float acc = 0.0f;
    size_t NN = (size_t)N;
    for (int i = start + sub; i < end; i += 8) {
        uint4 r = rec[i];
        float bx = bf2f((unsigned short)(r.x & 0xffffu));
        float by = bf2f((unsigned short)(r.x >> 16));
        float bz = bf2f((unsigned short)(r.y & 0xffffu));
        float bw = bf2f((unsigned short)(r.y >> 16));
        int s = (int)r.z;
        unsigned pA = r.w & 255u, pB = (r.w >> 8) & 255u;
        unsigned i1a = pA % 5u;
        unsigned d = (i1a < 4u) ? 1u : 0u;
        acc += bx * bf2f(y2Tb[(pA * NN + s) * 8 + c]);
        acc += by * bf2f(y2Tb[(pB * NN + s) * 8 + c]);
        acc += bz * bf2f(y2Tb[((pA + d) * NN + s) * 8 + c]);
        acc += bw * bf2f(y2Tb[((pB + d) * NN + s) * 8 + c]);
    }
    acc += __shfl_xor(acc, 8, 64);
    acc += __shfl_xor(acc, 16, 64);
    acc += __shfl_xor(acc, 32, 64);
    float inv = 1.0f / (float)max(end - start, 1);
    float z;
    if (c < CC) {
        z = acc * inv + bias2[c];
        const float* hrow = h1 + (size_t)n * 16;
#pragma unroll
        for (int i = 0; i < 16; i++) z += hrow[i] * root2[i * CC + c];
    } else {
        z = -1e30f;
    }
    float m = z;
    m = fmaxf(m, __shfl_xor(m, 1, 64));
    m = fmaxf(m, __shfl_xor(m, 2, 64));
    m = fmaxf(m, __shfl_xor(m, 4, 64));
    float ex = (c < CC) ? expf(z - m) : 0.0f;
    float ssum = ex;
    ssum += __shfl_xor(ssum, 1, 64);
    ssum += __shfl_xor(ssum, 2, 64);
    ssum += __shfl_xor(ssum, 4, 64);
    float ls = logf(ssum);
    if (lane < CC) out[(size_t)n * 7 + c] = z - m - ls;
}

extern "C" void kernel_launch(void* const* d_in, const int* in_sizes, int n_in,
                              void* d_out, int out_size, void* d_ws, size_t ws_size,
                              hipStream_t stream) {
    const float* x     = (const float*)d_in[0];
    const int*   ei    = (const int*)d_in[1];
    const float* attr  = (const float*)d_in[2];
    const float* W1    = (const float*)d_in[3];
    const float* root1 = (const float*)d_in[4];
    const float* bias1 = (const float*)d_in[5];
    const float* W2    = (const float*)d_in[6];
    const float* root2 = (const float*)d_in[7];
    const float* bias2 = (const float*)d_in[8];
    float* out = (float*)d_out;

    int N = in_sizes[0] / FIN;
    int E = in_sizes[1] / 2;

    char* w = (char*)d_ws;
    size_t off = 0;
    auto alloc = [&](size_t bytes) -> void* {
        void* p = w + off;
        off += (bytes + 255) & ~(size_t)255;
        return p;
    };
    int*      cnt      = (int*)alloc((size_t)N * 4);
    int*      rowStart = (int*)alloc((size_t)(N + 1) * 4);
    int*      cursor   = (int*)alloc((size_t)N * 4);
    int*      bsum     = (int*)alloc(260 * 4);
    int*      boff     = (int*)alloc(260 * 4);
    uint4*    rec      = (uint4*)alloc((size_t)E * 16);
    float*    h1       = (float*)alloc((size_t)N * 64);
    float*    B1t      = (float*)alloc((size_t)KK2 * FIN * HH * 4);
    float*    W2p      = (float*)alloc((size_t)KK2 * HH * 8 * 4);
    unsigned short* y1n  = (unsigned short*)alloc((size_t)N * 800 * 2);  // 80MB n-major pair-rows
    unsigned short* y2Tb = y1n;   // alias: y1n dead after k_agg1u; y2Tb is [25][N][8]
    (void)ws_size; (void)n_in; (void)out_size;

    hipMemsetAsync(cnt, 0, (size_t)N * 4, stream);

    int ebl = (E + 255) / 256;
    int nbl = (N + 255) / 256;
    int sblk = (N + SCAN_CHUNK - 1) / SCAN_CHUNK;   // 49 blocks for N=50k

    k_hist<<<ebl, 256, 0, stream>>>(ei, cnt, E);
    k_bsum<<<sblk, SCAN_BLK, 0, stream>>>(cnt, bsum, N);
    k_bscan<<<1, 256, 0, stream>>>(bsum, boff, sblk);
    k_sfin<<<sblk, SCAN_BLK, 0, stream>>>(cnt, boff, rowStart, cursor, N);
    k_scatter<<<ebl, 256, 0, stream>>>(attr, ei, cursor, rec, E);
    k_prepW<<<(KK2 * FIN * HH + 255) / 256, 256, 0, stream>>>(W1, W2, B1t, W2p);
    k_y1<<<5 * nbl, 256, 0, stream>>>(x, B1t, y1n, N, nbl);
    k_agg1u<<<(N + 3) / 4, 256, 0, stream>>>(rowStart, rec, y1n, x, root1, bias1, h1, N);
    k_y2<<<5 * nbl, 256, 0, stream>>>(h1, W2p, y2Tb, N, nbl);
    k_agg2f<<<(N + 3) / 4, 256, 0, stream>>>(rowStart, rec, y2Tb, h1, root2, bias2, out, N);
}